// Round 10
// baseline (261.870 us; speedup 1.0000x reference)
//
#include <hip/hip_runtime.h>

#define BS 4
#define NN 256
#define DX 256
#define DE 64
#define DY 64
#define INV_SQRT_DF 0.17677669529663687f

typedef unsigned short ushort_t;
typedef unsigned int uint32;
typedef short v4s __attribute__((ext_vector_type(4)));
typedef float v4f __attribute__((ext_vector_type(4)));
typedef uint32 v4u __attribute__((ext_vector_type(4)));

__device__ __forceinline__ float b2f(ushort_t u) {
  union { uint32 i; float f; } v; v.i = ((uint32)u) << 16; return v.f;
}
__device__ __forceinline__ ushort_t f2b(float f) {
  union { float f; uint32 i; } v; v.f = f;
  uint32 x = v.i;
  x += ((x >> 16) & 1u) + 0x7FFFu;   // round-to-nearest-even
  return (ushort_t)(x >> 16);
}

#define SWZ_ET(jl, kb)  ((((jl) << 7) + (kb)) ^ (((jl) & 7) << 4))
#define SWZ_PRE(jl, kb) ((((jl) << 9) + (kb)) ^ (((jl) & 7) << 4))

// =================== k_pre ===================
// blocks 0..95: QKV GEMM (o = blk>>5, Mtile=32); 96..127: X stats; 128..131: ymul
__global__ __launch_bounds__(512) void k_pre(
    const float* __restrict__ X, const float* __restrict__ nmask, const float* __restrict__ y,
    const float* __restrict__ Wq, const float* __restrict__ bq,
    const float* __restrict__ Wk, const float* __restrict__ bk,
    const float* __restrict__ Wv, const float* __restrict__ bv,
    const float* __restrict__ Wye, const float* __restrict__ bye,
    const float* __restrict__ Wyx, const float* __restrict__ byx,
    float* __restrict__ Q, float* __restrict__ K, float* __restrict__ V,
    float* __restrict__ xp, float* __restrict__ yep1, float* __restrict__ yxp1) {
  __shared__ char SM[16384];
  int blk = blockIdx.x, t = threadIdx.x;
  if (blk < 96) {
    int o = blk >> 5; int m = blk & 31; int b = m >> 3, itile = m & 7;
    // stage X tile (32 x 256) f32 -> bf16 swizzled LDS
    #pragma unroll
    for (int h = 0; h < 2; ++h) {
      int idx = (t + (h << 9)) << 3;
      int row = idx >> 8, d0 = idx & 255;
      const float* src = X + ((((size_t)(b << 8) + (itile << 5) + row)) << 8) + d0;
      float4 v0 = *(const float4*)src;
      float4 v1 = *(const float4*)(src + 4);
      v4u p;
      p[0] = f2b(v0.x) | ((uint32)f2b(v0.y) << 16);
      p[1] = f2b(v0.z) | ((uint32)f2b(v0.w) << 16);
      p[2] = f2b(v1.x) | ((uint32)f2b(v1.y) << 16);
      p[3] = f2b(v1.z) | ((uint32)f2b(v1.w) << 16);
      *(v4u*)(SM + SWZ_PRE(row, d0 << 1)) = p;
    }
    __syncthreads();
    int w = t >> 6, lane = t & 63, lg = lane >> 4, lr = lane & 15;
    int n0 = w << 5;
    const float* W = (o == 0) ? Wq : (o == 1) ? Wk : Wv;
    const float* B = (o == 0) ? bq : (o == 1) ? bk : bv;
    float* O = (o == 0) ? Q : (o == 1) ? K : V;
    const v4f vz = {0.f, 0.f, 0.f, 0.f};
    v4s bw[2][16];
    #pragma unroll
    for (int cr = 0; cr < 2; ++cr)
      #pragma unroll
      for (int ks = 0; ks < 16; ++ks) {
        int kk = (ks << 4) + (lg << 2);
        v4s f;
        #pragma unroll
        for (int e = 0; e < 4; ++e) f[e] = (short)f2b(W[(kk + e) * DX + n0 + (cr << 4) + lr]);
        bw[cr][ks] = f;
      }
    v4f acc[2][2];
    acc[0][0] = vz; acc[0][1] = vz; acc[1][0] = vz; acc[1][1] = vz;
    #pragma unroll
    for (int ks = 0; ks < 16; ++ks) {
      v4s A[2];
      #pragma unroll
      for (int ir = 0; ir < 2; ++ir) {
        int il = (ir << 4) + lr;
        A[ir] = *(const v4s*)(SM + SWZ_PRE(il, (ks << 5) + (lg << 3)));
      }
      #pragma unroll
      for (int ir = 0; ir < 2; ++ir)
        #pragma unroll
        for (int cr = 0; cr < 2; ++cr)
          acc[ir][cr] = __builtin_amdgcn_mfma_f32_16x16x16bf16_1k(A[ir], bw[cr][ks], acc[ir][cr], 0, 0, 0);
    }
    float bb[2] = {B[n0 + lr], B[n0 + 16 + lr]};
    #pragma unroll
    for (int ir = 0; ir < 2; ++ir)
      #pragma unroll
      for (int rg = 0; rg < 4; ++rg) {
        int gi = (b << 8) + (itile << 5) + (ir << 4) + (lg << 2) + rg;
        float mi = nmask[gi];
        size_t orow = (size_t)gi << 8;
        O[orow + n0 + lr]      = (acc[ir][0][rg] + bb[0]) * mi;
        O[orow + n0 + 16 + lr] = (acc[ir][1][rg] + bb[1]) * mi;
      }
  } else if (blk < 128) {
    if (t < 256) {
      int idx2 = blk - 96; int b = idx2 >> 3, ch = idx2 & 7;
      float s = 0.f, ss = 0.f, mn = 3e38f, mx = -3e38f;
      #pragma unroll 4
      for (int r = 0; r < 32; ++r) {
        float v = X[(((size_t)(b << 8) + (ch << 5) + r) << 8) + t];
        s += v; ss += v * v; mn = fminf(mn, v); mx = fmaxf(mx, v);
      }
      float* o2 = xp + ((size_t)((b << 3) + ch) << 10);
      o2[t] = s; o2[256 + t] = mn; o2[512 + t] = mx; o2[768 + t] = ss;
    }
  } else {
    int b = blk - 128;
    float* sy = (float*)SM;
    if (t < 64) sy[t] = y[(b << 6) + t];
    __syncthreads();
    if (t < 256) {
      float ae = bye[t], ax = byx[t];
      #pragma unroll
      for (int k = 0; k < DY; ++k) {
        float v = sy[k];
        ae += v * Wye[k * DX + t];
        ax += v * Wyx[k * DX + t];
      }
      yep1[(b << 8) + t] = ae + 1.0f;
      yxp1[(b << 8) + t] = ax + 1.0f;
    }
  }
}

// =================== k_main: round-3 structure + batched softmax ===================
#define ET_OFF 0
#define PRE_OFF 8192
#define RED_OFF 40960

__global__ __launch_bounds__(512, 2) void k_main(
    const float* __restrict__ E, const float* __restrict__ nmask,
    const float* __restrict__ Wemul, const float* __restrict__ bemul,
    const float* __restrict__ Weout, const float* __restrict__ beout,
    const float* __restrict__ Q, const float* __restrict__ Kf, const float* __restrict__ Vf,
    const float* __restrict__ yep1, const float* __restrict__ yxp1,
    float* __restrict__ newE, float* __restrict__ wvs, float* __restrict__ est) {
  __shared__ char SM[49152];
  int t = threadIdx.x;
  int blk = blockIdx.x; int b = blk >> 8;
  int w = t >> 6, lane = t & 63, lg = lane >> 4, lr = lane & 15;

  float mi = nmask[blk];

  // per-lane constants (GEMM1/softmax side)
  int cc[2]; float qv[2], yev[2], yxv[2], bemv[2];
  #pragma unroll
  for (int cr = 0; cr < 2; ++cr) {
    int c = (w << 5) + (cr << 4) + lr;
    cc[cr] = c;
    qv[cr]  = Q[(size_t)blk * DX + c];
    yev[cr] = yep1[(b << 8) + c];
    yxv[cr] = yxp1[(b << 8) + c];
    bemv[cr] = bemul[c];
  }
  // GEMM2 side
  int jq = w >> 1, dh = w & 1;
  int dd[2]; float beoV[2];
  #pragma unroll
  for (int dr = 0; dr < 2; ++dr) { int d = (dh << 5) + (dr << 4) + lr; dd[dr] = d; beoV[dr] = beout[d]; }

  // hoisted B-fragments, loaded straight from global (f32 -> bf16 pack)
  v4s bfr1[2][4];
  #pragma unroll
  for (int cr = 0; cr < 2; ++cr)
    #pragma unroll
    for (int ks = 0; ks < 4; ++ks) {
      int k0 = (ks << 4) + (lg << 2);
      v4s f;
      #pragma unroll
      for (int e = 0; e < 4; ++e) f[e] = (short)f2b(Wemul[(k0 + e) * DX + cc[cr]]);
      bfr1[cr][ks] = f;
    }
  v4s bfr2[2][16];
  #pragma unroll
  for (int dr = 0; dr < 2; ++dr)
    #pragma unroll
    for (int ks = 0; ks < 16; ++ks) {
      int c0 = (ks << 4) + (lg << 2);
      v4s f;
      #pragma unroll
      for (int e = 0; e < 4; ++e) f[e] = (short)f2b(Weout[(c0 + e) * DE + dd[dr]]);
      bfr2[dr][ks] = f;
    }

  float mloc[2] = {-3e38f, -3e38f}, lloc[2] = {0.f, 0.f}, avloc[2] = {0.f, 0.f};
  float es_s = 0.f, es_ss = 0.f, es_mn = 3e38f, es_mx = -3e38f;

  const float* Erow = E + (size_t)blk * (NN * DE);
  const v4f vzero = {0.f, 0.f, 0.f, 0.f};

  for (int jt = 0; jt < 4; ++jt) {
    __syncthreads();   // prior GEMM1 (ET) and GEMM2 (PRE) reads complete
    // ---- stage E tile (f32 global -> bf16 LDS, swizzled) + E-stat partials ----
    #pragma unroll
    for (int it = 0; it < 8; ++it) {
      int idx = t + (it << 9);
      int jl = idx >> 6, k = idx & 63;
      float v = Erow[(jt << 12) + idx];
      es_s += v; es_ss += v * v; es_mn = fminf(es_mn, v); es_mx = fmaxf(es_mx, v);
      *(ushort_t*)(SM + ET_OFF + (((jl << 7) + (k << 1)) ^ ((jl & 7) << 4))) = f2b(v);
    }
    __syncthreads();

    // ---- GEMM1: E1 = ET(64x64) @ Wemul(64x256), wave's 32-col slice ----
    v4f acc1[4][2];
    #pragma unroll
    for (int jr = 0; jr < 4; ++jr)
      #pragma unroll
      for (int cr = 0; cr < 2; ++cr) acc1[jr][cr] = vzero;
    #pragma unroll
    for (int ks = 0; ks < 4; ++ks) {
      v4s aA[4];
      #pragma unroll
      for (int jr = 0; jr < 4; ++jr) {
        int jl = (jr << 4) + lr;
        aA[jr] = *(const v4s*)(SM + ET_OFF + (((jl << 7) + (ks << 5) + (lg << 3)) ^ ((jl & 7) << 4)));
      }
      #pragma unroll
      for (int jr = 0; jr < 4; ++jr)
        #pragma unroll
        for (int cr = 0; cr < 2; ++cr)
          acc1[jr][cr] = __builtin_amdgcn_mfma_f32_16x16x16bf16_1k(aA[jr], bfr1[cr][ks], acc1[jr][cr], 0, 0, 0);
    }

    // ---- elementwise: Y, BATCHED online softmax (per 4-reg quad), pre -> LDS ----
    #pragma unroll
    for (int jr = 0; jr < 4; ++jr) {
      #pragma unroll
      for (int cr = 0; cr < 2; ++cr) {
        float yvv[4], vv[4];
        #pragma unroll
        for (int reg = 0; reg < 4; ++reg) {
          int jl = (jr << 4) + (lg << 2) + reg;
          int j = (jt << 6) + jl;
          float mj = nmask[(b << 8) + j];
          size_t rowKV = (((size_t)(b << 8) + j) << 8);
          float E1 = (acc1[jr][cr][reg] + bemv[cr]) * (mi * mj);
          float Yv = qv[cr] * Kf[rowKV + cc[cr]] * INV_SQRT_DF * (E1 + 1.0f);
          *(ushort_t*)(SM + PRE_OFF + (((jl << 9) + (cc[cr] << 1)) ^ ((jl & 7) << 4))) = f2b(yev[cr] * Yv);
          yvv[reg] = (mj > 0.f) ? Yv : -3e38f;
          vv[reg] = Vf[rowKV + cc[cr]];
        }
        float pm = fmaxf(fmaxf(yvv[0], yvv[1]), fmaxf(yvv[2], yvv[3]));
        float nm = fmaxf(mloc[cr], pm);
        float corr = __expf(mloc[cr] - nm);
        float ps = 0.f, pv = 0.f;
        #pragma unroll
        for (int reg = 0; reg < 4; ++reg) {
          float p = __expf(yvv[reg] - nm);
          ps += p; pv += p * vv[reg];
        }
        lloc[cr] = lloc[cr] * corr + ps;
        avloc[cr] = avloc[cr] * corr + pv;
        mloc[cr] = nm;
      }
    }
    __syncthreads();   // PRE ready

    // ---- GEMM2: newE_tile = PRE(64x256) @ Weout(256x64); wave: 16j x 32d ----
    v4f acc2[2] = {vzero, vzero};
    #pragma unroll
    for (int ks = 0; ks < 16; ++ks) {
      int jl = (jq << 4) + lr;
      v4s aA = *(const v4s*)(SM + PRE_OFF + (((jl << 9) + (ks << 5) + (lg << 3)) ^ ((jl & 7) << 4)));
      acc2[0] = __builtin_amdgcn_mfma_f32_16x16x16bf16_1k(aA, bfr2[0][ks], acc2[0], 0, 0, 0);
      acc2[1] = __builtin_amdgcn_mfma_f32_16x16x16bf16_1k(aA, bfr2[1][ks], acc2[1], 0, 0, 0);
    }
    // epilogue: write newE rows of this j-tile
    #pragma unroll
    for (int reg = 0; reg < 4; ++reg) {
      int j = (jt << 6) + (jq << 4) + (lg << 2) + reg;
      float mj = nmask[(b << 8) + j];
      float mm = mi * mj;
      size_t orow = (((size_t)blk << 8) + j) << 6;
      #pragma unroll
      for (int dr = 0; dr < 2; ++dr)
        newE[orow + dd[dr]] = (acc2[dr][reg] + beoV[dr]) * mm;
    }
  }

  // ---- softmax merge across the 4 lane-groups; write wvs ----
  #pragma unroll
  for (int cr = 0; cr < 2; ++cr) {
    #pragma unroll
    for (int off = 16; off <= 32; off <<= 1) {
      float m2 = __shfl_xor(mloc[cr], off, 64);
      float l2 = __shfl_xor(lloc[cr], off, 64);
      float a2 = __shfl_xor(avloc[cr], off, 64);
      float nm = fmaxf(mloc[cr], m2);
      float f1 = __expf(mloc[cr] - nm), f2n = __expf(m2 - nm);
      lloc[cr] = lloc[cr] * f1 + l2 * f2n;
      avloc[cr] = avloc[cr] * f1 + a2 * f2n;
      mloc[cr] = nm;
    }
    if (lg == 0)
      wvs[(size_t)blk * DX + cc[cr]] = yxv[cr] * (avloc[cr] / lloc[cr]);
  }

  // ---- E-stat block reduction ----
  float* RED = (float*)(SM + RED_OFF);
  RED[t] = es_s; RED[512 + t] = es_mn; RED[1024 + t] = es_mx; RED[1536 + t] = es_ss;
  __syncthreads();
  if (t < 64) {
    float s = 0.f, ss = 0.f, mn = 3e38f, mx = -3e38f;
    #pragma unroll
    for (int q = 0; q < 8; ++q) {
      s  += RED[t + (q << 6)];
      mn  = fminf(mn, RED[512 + t + (q << 6)]);
      mx  = fmaxf(mx, RED[1024 + t + (q << 6)]);
      ss += RED[1536 + t + (q << 6)];
    }
    float* eb = est + ((size_t)blk << 8);
    eb[t] = s; eb[64 + t] = mn; eb[128 + t] = mx; eb[192 + t] = ss;
  }
}

// =================== k_post: newX MFMA GEMM (Mtile=32) + y path ===================
// blocks 0..31: newX; 32..35: y path
__global__ __launch_bounds__(512) void k_post(
    const float* __restrict__ wvs, const float* __restrict__ Wxo, const float* __restrict__ bxo,
    const float* __restrict__ nmask, const float* __restrict__ y,
    const float* __restrict__ xp, const float* __restrict__ est,
    const float* __restrict__ Wyy, const float* __restrict__ byy,
    const float* __restrict__ Wxy, const float* __restrict__ bxy,
    const float* __restrict__ Wey, const float* __restrict__ bey,
    const float* __restrict__ W1, const float* __restrict__ b1,
    const float* __restrict__ W2, const float* __restrict__ b2_,
    float* __restrict__ newX, float* __restrict__ newy) {
  __shared__ char SM[16384];
  int blk = blockIdx.x, t = threadIdx.x;
  if (blk < 32) {
    int b = blk >> 3, it = blk & 7;
    #pragma unroll
    for (int h = 0; h < 2; ++h) {
      int idx = (t + (h << 9)) << 3;
      int row = idx >> 8, d0 = idx & 255;
      const float* src = wvs + ((((size_t)(b << 8) + (it << 5) + row)) << 8) + d0;
      float4 v0 = *(const float4*)src;
      float4 v1 = *(const float4*)(src + 4);
      v4u p;
      p[0] = f2b(v0.x) | ((uint32)f2b(v0.y) << 16);
      p[1] = f2b(v0.z) | ((uint32)f2b(v0.w) << 16);
      p[2] = f2b(v1.x) | ((uint32)f2b(v1.y) << 16);
      p[3] = f2b(v1.z) | ((uint32)f2b(v1.w) << 16);
      *(v4u*)(SM + SWZ_PRE(row, d0 << 1)) = p;
    }
    __syncthreads();
    int w = t >> 6, lane = t & 63, lg = lane >> 4, lr = lane & 15;
    int n0 = w << 5;
    const v4f vz = {0.f, 0.f, 0.f, 0.f};
    v4s bw[2][16];
    #pragma unroll
    for (int cr = 0; cr < 2; ++cr)
      #pragma unroll
      for (int ks = 0; ks < 16; ++ks) {
        int kk = (ks << 4) + (lg << 2);
        v4s f;
        #pragma unroll
        for (int e = 0; e < 4; ++e) f[e] = (short)f2b(Wxo[(kk + e) * DX + n0 + (cr << 4) + lr]);
        bw[cr][ks] = f;
      }
    v4f acc[2][2];
    acc[0][0] = vz; acc[0][1] = vz; acc[1][0] = vz; acc[1][1] = vz;
    #pragma unroll
    for (int ks = 0; ks < 16; ++ks) {
      v4s A[2];
      #pragma unroll
      for (int ir = 0; ir < 2; ++ir) {
        int il = (ir << 4) + lr;
        A[ir] = *(const v4s*)(SM + SWZ_PRE(il, (ks << 5) + (lg << 3)));
      }
      #pragma unroll
      for (int ir = 0; ir < 2; ++ir)
        #pragma unroll
        for (int cr = 0; cr < 2; ++cr)
          acc[ir][cr] = __builtin_amdgcn_mfma_f32_16x16x16bf16_1k(A[ir], bw[cr][ks], acc[ir][cr], 0, 0, 0);
    }
    float bb[2] = {bxo[n0 + lr], bxo[n0 + 16 + lr]};
    #pragma unroll
    for (int ir = 0; ir < 2; ++ir)
      #pragma unroll
      for (int rg = 0; rg < 4; ++rg) {
        int i = (it << 5) + (ir << 4) + (lg << 2) + rg;
        float mi = nmask[(b << 8) + i];
        size_t orow = ((size_t)(b << 8) + i) << 8;
        #pragma unroll
        for (int cr = 0; cr < 2; ++cr)
          newX[orow + n0 + (cr << 4) + lr] = (acc[ir][cr][rg] + bb[cr]) * mi;
      }
  } else {
    int b = blk - 32;
    float* sxs  = (float*)SM;        // 1024
    float* ses  = sxs + 1024;        // 256
    float* red  = ses + 256;         // 256
    float* red2 = red + 256;         // 512
    float* sny  = red2 + 512;        // 64
    float* sh   = sny + 64;          // 64
    float* sy   = sh + 64;           // 64
    // phase A: est raw reduce (512 threads, 2 i-halves) + xs finish + sy
    {
      int g = t >> 8, tt = t & 255, s = tt >> 6;
      float r = (s == 1) ? 3e38f : ((s == 2) ? -3e38f : 0.f);
      #pragma unroll 8
      for (int i2 = 0; i2 < 128; ++i2) {
        float x = est[(((size_t)(b << 8) + (g << 7) + i2) << 8) + tt];
        if (s == 0 || s == 3) r += x; else if (s == 1) r = fminf(r, x); else r = fmaxf(r, x);
      }
      red2[t] = r;
    }
    if (t < 256) {
      float meanv = 0.f;
      #pragma unroll
      for (int v = 0; v < 4; ++v) {
        float r = (v == 1) ? 3e38f : ((v == 2) ? -3e38f : 0.f);
        #pragma unroll
        for (int ch = 0; ch < 8; ++ch) {
          float x = xp[((size_t)(((b << 3) + ch) << 2) + v) * 256 + t];
          if (v == 0 || v == 3) r += x; else if (v == 1) r = fminf(r, x); else r = fmaxf(r, x);
        }
        float outv;
        if (v == 0) { meanv = r * (1.f / 256.f); outv = meanv; }
        else if (v == 3) { float var = (r - 256.f * meanv * meanv) * (1.f / 255.f); outv = sqrtf(fmaxf(var, 0.f)); }
        else outv = r;
        sxs[(v << 8) + t] = outv;
      }
    }
    if (t < 64) sy[t] = y[(b << 6) + t];
    __syncthreads();
    if (t < 256) {
      int s = (t & 255) >> 6;
      float a = red2[t], b2v = red2[256 + t];
      red[t] = (s == 0 || s == 3) ? (a + b2v) : (s == 1 ? fminf(a, b2v) : fmaxf(a, b2v));
    }
    __syncthreads();
    // phase B: est finish
    if (t < 256) {
      int stat = t >> 6, d = t & 63;
      float meanv = red[d] * (1.f / 65536.f);
      float outv;
      if (stat == 0) outv = meanv;
      else if (stat == 1) outv = red[64 + d];
      else if (stat == 2) outv = red[128 + d];
      else { float var = (red[192 + d] - 65536.f * meanv * meanv) * (1.f / 65535.f); outv = sqrtf(fmaxf(var, 0.f)); }
      ses[t] = outv;
    }
    __syncthreads();
    // phase C: big GEMV partials (split-k 4)
    int kq = t >> 6, d = t & 63;
    if (t < 256) {
      float acc = 0.f;
      #pragma unroll 4
      for (int k = kq << 4; k < (kq << 4) + 16; ++k) acc += sy[k] * Wyy[k * DY + d];
      for (int k = kq << 8; k < (kq << 8) + 256; ++k) acc += sxs[k] * Wxy[k * DY + d];
      #pragma unroll 4
      for (int k = kq << 6; k < (kq << 6) + 64; ++k) acc += ses[k] * Wey[k * DY + d];
      red[t] = acc;
    }
    __syncthreads();
    if (t < 64) sny[t] = red[t] + red[64 + t] + red[128 + t] + red[192 + t] + byy[t] + bxy[t] + bey[t];
    __syncthreads();
    if (t < 256) {
      float a = 0.f;
      #pragma unroll 4
      for (int k = kq << 4; k < (kq << 4) + 16; ++k) a += sny[k] * W1[k * DY + d];
      red[t] = a;
    }
    __syncthreads();
    if (t < 64) sh[t] = fmaxf(red[t] + red[64 + t] + red[128 + t] + red[192 + t] + b1[t], 0.f);
    __syncthreads();
    if (t < 256) {
      float a = 0.f;
      #pragma unroll 4
      for (int k = kq << 4; k < (kq << 4) + 16; ++k) a += sh[k] * W2[k * DY + d];
      red[t] = a;
    }
    __syncthreads();
    if (t < 64) newy[(b << 6) + t] = red[t] + red[64 + t] + red[128 + t] + red[192 + t] + b2_[t];
  }
}

extern "C" void kernel_launch(void* const* d_in, const int* in_sizes, int n_in,
                              void* d_out, int out_size, void* d_ws, size_t ws_size,
                              hipStream_t stream) {
  (void)in_sizes; (void)n_in; (void)out_size; (void)ws_size;
  const float* X   = (const float*)d_in[0];
  const float* E   = (const float*)d_in[1];
  const float* y   = (const float*)d_in[2];
  const float* nm  = (const float*)d_in[3];
  const float* Wq  = (const float*)d_in[4];  const float* bq  = (const float*)d_in[5];
  const float* Wk  = (const float*)d_in[6];  const float* bk  = (const float*)d_in[7];
  const float* Wv  = (const float*)d_in[8];  const float* bv  = (const float*)d_in[9];
  const float* Wem = (const float*)d_in[10]; const float* bem = (const float*)d_in[11];
  const float* Wye = (const float*)d_in[12]; const float* bye = (const float*)d_in[13];
  const float* Wyx = (const float*)d_in[14]; const float* byx = (const float*)d_in[15];
  const float* Wyy = (const float*)d_in[16]; const float* byy = (const float*)d_in[17];
  const float* Wxy = (const float*)d_in[18]; const float* bxy = (const float*)d_in[19];
  const float* Wey = (const float*)d_in[20]; const float* bey = (const float*)d_in[21];
  const float* Wxo = (const float*)d_in[22]; const float* bxo = (const float*)d_in[23];
  const float* Weo = (const float*)d_in[24]; const float* beo = (const float*)d_in[25];
  const float* W1  = (const float*)d_in[26]; const float* b1  = (const float*)d_in[27];
  const float* W2  = (const float*)d_in[28]; const float* b2  = (const float*)d_in[29];

  float* ws   = (float*)d_ws;
  float* Q    = ws;                 // 262144
  float* K    = Q + 262144;         // 262144
  float* V    = K + 262144;         // 262144
  float* yep1 = V + 262144;         // 1024
  float* yxp1 = yep1 + 1024;        // 1024
  float* wvs  = yxp1 + 1024;        // 262144
  float* est  = wvs + 262144;       // 262144
  float* xp   = est + 262144;       // 32768

  float* newX = (float*)d_out;
  float* newE = newX + 262144;
  float* newy = newE + 16777216;

  k_pre<<<132, 512, 0, stream>>>(X, nm, y, Wq, bq, Wk, bk, Wv, bv, Wye, bye, Wyx, byx,
                                 Q, K, V, xp, yep1, yxp1);
  k_main<<<BS * NN, 512, 0, stream>>>(E, nm, Wem, bem, Weo, beo, Q, K, V, yep1, yxp1,
                                      newE, wvs, est);
  k_post<<<36, 512, 0, stream>>>(wvs, Wxo, bxo, nm, y, xp, est,
                                 Wyy, byy, Wxy, bxy, Wey, bey, W1, b1, W2, b2, newX, newy);
}

// Round 11
// 193.164 us; speedup vs baseline: 1.3557x; 1.3557x over previous
//
#include <hip/hip_runtime.h>

#define BS 4
#define NN 256
#define DX 256
#define DE 64
#define DY 64
#define INV_SQRT_DF 0.17677669529663687f

typedef unsigned short ushort_t;
typedef unsigned int uint32;
typedef short v4s __attribute__((ext_vector_type(4)));
typedef float v4f __attribute__((ext_vector_type(4)));
typedef uint32 v4u __attribute__((ext_vector_type(4)));

__device__ __forceinline__ float b2f(ushort_t u) {
  union { uint32 i; float f; } v; v.i = ((uint32)u) << 16; return v.f;
}
__device__ __forceinline__ ushort_t f2b(float f) {
  union { float f; uint32 i; } v; v.f = f;
  uint32 x = v.i;
  x += ((x >> 16) & 1u) + 0x7FFFu;   // round-to-nearest-even
  return (ushort_t)(x >> 16);
}

#define SWZ_ET(jl, kb)  ((((jl) << 7) + (kb)) ^ (((jl) & 7) << 4))
#define SWZ_PRE(jl, kb) ((((jl) << 9) + (kb)) ^ (((jl) & 7) << 4))

// =================== k_pre ===================
// blocks 0..95: QKV GEMM (o = blk>>5, Mtile=32); 96..127: X stats; 128..131: ymul
__global__ __launch_bounds__(512) void k_pre(
    const float* __restrict__ X, const float* __restrict__ nmask, const float* __restrict__ y,
    const float* __restrict__ Wq, const float* __restrict__ bq,
    const float* __restrict__ Wk, const float* __restrict__ bk,
    const float* __restrict__ Wv, const float* __restrict__ bv,
    const float* __restrict__ Wye, const float* __restrict__ bye,
    const float* __restrict__ Wyx, const float* __restrict__ byx,
    float* __restrict__ Q, float* __restrict__ K, float* __restrict__ V,
    float* __restrict__ xp, float* __restrict__ yep1, float* __restrict__ yxp1) {
  __shared__ char SM[16384];
  int blk = blockIdx.x, t = threadIdx.x;
  if (blk < 96) {
    int o = blk >> 5; int m = blk & 31; int b = m >> 3, itile = m & 7;
    // stage X tile (32 x 256) f32 -> bf16 swizzled LDS
    #pragma unroll
    for (int h = 0; h < 2; ++h) {
      int idx = (t + (h << 9)) << 3;
      int row = idx >> 8, d0 = idx & 255;
      const float* src = X + ((((size_t)(b << 8) + (itile << 5) + row)) << 8) + d0;
      float4 v0 = *(const float4*)src;
      float4 v1 = *(const float4*)(src + 4);
      v4u p;
      p[0] = f2b(v0.x) | ((uint32)f2b(v0.y) << 16);
      p[1] = f2b(v0.z) | ((uint32)f2b(v0.w) << 16);
      p[2] = f2b(v1.x) | ((uint32)f2b(v1.y) << 16);
      p[3] = f2b(v1.z) | ((uint32)f2b(v1.w) << 16);
      *(v4u*)(SM + SWZ_PRE(row, d0 << 1)) = p;
    }
    __syncthreads();
    int w = t >> 6, lane = t & 63, lg = lane >> 4, lr = lane & 15;
    int n0 = w << 5;
    const float* W = (o == 0) ? Wq : (o == 1) ? Wk : Wv;
    const float* B = (o == 0) ? bq : (o == 1) ? bk : bv;
    float* O = (o == 0) ? Q : (o == 1) ? K : V;
    const v4f vz = {0.f, 0.f, 0.f, 0.f};
    v4s bw[2][16];
    #pragma unroll
    for (int cr = 0; cr < 2; ++cr)
      #pragma unroll
      for (int ks = 0; ks < 16; ++ks) {
        int kk = (ks << 4) + (lg << 2);
        v4s f;
        #pragma unroll
        for (int e = 0; e < 4; ++e) f[e] = (short)f2b(W[(kk + e) * DX + n0 + (cr << 4) + lr]);
        bw[cr][ks] = f;
      }
    v4f acc[2][2];
    acc[0][0] = vz; acc[0][1] = vz; acc[1][0] = vz; acc[1][1] = vz;
    #pragma unroll
    for (int ks = 0; ks < 16; ++ks) {
      v4s A[2];
      #pragma unroll
      for (int ir = 0; ir < 2; ++ir) {
        int il = (ir << 4) + lr;
        A[ir] = *(const v4s*)(SM + SWZ_PRE(il, (ks << 5) + (lg << 3)));
      }
      #pragma unroll
      for (int ir = 0; ir < 2; ++ir)
        #pragma unroll
        for (int cr = 0; cr < 2; ++cr)
          acc[ir][cr] = __builtin_amdgcn_mfma_f32_16x16x16bf16_1k(A[ir], bw[cr][ks], acc[ir][cr], 0, 0, 0);
    }
    float bb[2] = {B[n0 + lr], B[n0 + 16 + lr]};
    #pragma unroll
    for (int ir = 0; ir < 2; ++ir)
      #pragma unroll
      for (int rg = 0; rg < 4; ++rg) {
        int gi = (b << 8) + (itile << 5) + (ir << 4) + (lg << 2) + rg;
        float mi = nmask[gi];
        size_t orow = (size_t)gi << 8;
        O[orow + n0 + lr]      = (acc[ir][0][rg] + bb[0]) * mi;
        O[orow + n0 + 16 + lr] = (acc[ir][1][rg] + bb[1]) * mi;
      }
  } else if (blk < 128) {
    if (t < 256) {
      int idx2 = blk - 96; int b = idx2 >> 3, ch = idx2 & 7;
      float s = 0.f, ss = 0.f, mn = 3e38f, mx = -3e38f;
      #pragma unroll 4
      for (int r = 0; r < 32; ++r) {
        float v = X[(((size_t)(b << 8) + (ch << 5) + r) << 8) + t];
        s += v; ss += v * v; mn = fminf(mn, v); mx = fmaxf(mx, v);
      }
      float* o2 = xp + ((size_t)((b << 3) + ch) << 10);
      o2[t] = s; o2[256 + t] = mn; o2[512 + t] = mx; o2[768 + t] = ss;
    }
  } else {
    int b = blk - 128;
    float* sy = (float*)SM;
    if (t < 64) sy[t] = y[(b << 6) + t];
    __syncthreads();
    if (t < 256) {
      float ae = bye[t], ax = byx[t];
      #pragma unroll
      for (int k = 0; k < DY; ++k) {
        float v = sy[k];
        ae += v * Wye[k * DX + t];
        ax += v * Wyx[k * DX + t];
      }
      yep1[(b << 8) + t] = ae + 1.0f;
      yxp1[(b << 8) + t] = ax + 1.0f;
    }
  }
}

// =================== k_main: EXACT round-9 structure (proven 148us); qv pre-scaled ===================
#define ET_OFF 0
#define PRE_OFF 8192
#define RED_OFF 40960

__global__ __launch_bounds__(512, 2) void k_main(
    const float* __restrict__ E, const float* __restrict__ nmask,
    const float* __restrict__ Wemul, const float* __restrict__ bemul,
    const float* __restrict__ Weout, const float* __restrict__ beout,
    const float* __restrict__ Q, const float* __restrict__ Kf, const float* __restrict__ Vf,
    const float* __restrict__ yep1, const float* __restrict__ yxp1,
    float* __restrict__ newE, float* __restrict__ wvs, float* __restrict__ est) {
  __shared__ char SM[49152];
  int t = threadIdx.x;
  int blk = blockIdx.x; int b = blk >> 8;
  int w = t >> 6, lane = t & 63, lg = lane >> 4, lr = lane & 15;

  float mi = nmask[blk];

  // per-lane constants (GEMM1/softmax side)
  int cc[2]; float qv[2], yev[2], yxv[2], bemv[2];
  #pragma unroll
  for (int cr = 0; cr < 2; ++cr) {
    int c = (w << 5) + (cr << 4) + lr;
    cc[cr] = c;
    qv[cr]  = Q[(size_t)blk * DX + c] * INV_SQRT_DF;
    yev[cr] = yep1[(b << 8) + c];
    yxv[cr] = yxp1[(b << 8) + c];
    bemv[cr] = bemul[c];
  }
  // GEMM2 side
  int jq = w >> 1, dh = w & 1;
  int dd[2]; float beoV[2];
  #pragma unroll
  for (int dr = 0; dr < 2; ++dr) { int d = (dh << 5) + (dr << 4) + lr; dd[dr] = d; beoV[dr] = beout[d]; }

  // hoisted B-fragments, loaded straight from global (f32 -> bf16 pack)
  v4s bfr1[2][4];
  #pragma unroll
  for (int cr = 0; cr < 2; ++cr)
    #pragma unroll
    for (int ks = 0; ks < 4; ++ks) {
      int k0 = (ks << 4) + (lg << 2);
      v4s f;
      #pragma unroll
      for (int e = 0; e < 4; ++e) f[e] = (short)f2b(Wemul[(k0 + e) * DX + cc[cr]]);
      bfr1[cr][ks] = f;
    }
  v4s bfr2[2][16];
  #pragma unroll
  for (int dr = 0; dr < 2; ++dr)
    #pragma unroll
    for (int ks = 0; ks < 16; ++ks) {
      int c0 = (ks << 4) + (lg << 2);
      v4s f;
      #pragma unroll
      for (int e = 0; e < 4; ++e) f[e] = (short)f2b(Weout[(c0 + e) * DE + dd[dr]]);
      bfr2[dr][ks] = f;
    }

  float mloc[2] = {-3e38f, -3e38f}, lloc[2] = {0.f, 0.f}, avloc[2] = {0.f, 0.f};
  float es_s = 0.f, es_ss = 0.f, es_mn = 3e38f, es_mx = -3e38f;

  const float* Erow = E + (size_t)blk * (NN * DE);
  const v4f vzero = {0.f, 0.f, 0.f, 0.f};

  for (int jt = 0; jt < 4; ++jt) {
    __syncthreads();   // prior GEMM1 (ET) and GEMM2 (PRE) reads complete
    // ---- stage E tile (f32 global -> bf16 LDS, swizzled) + E-stat partials ----
    #pragma unroll
    for (int it = 0; it < 8; ++it) {
      int idx = t + (it << 9);
      int jl = idx >> 6, k = idx & 63;
      float v = Erow[(jt << 12) + idx];
      es_s += v; es_ss += v * v; es_mn = fminf(es_mn, v); es_mx = fmaxf(es_mx, v);
      *(ushort_t*)(SM + ET_OFF + (((jl << 7) + (k << 1)) ^ ((jl & 7) << 4))) = f2b(v);
    }
    __syncthreads();

    // ---- GEMM1: E1 = ET(64x64) @ Wemul(64x256), wave's 32-col slice ----
    v4f acc1[4][2];
    #pragma unroll
    for (int jr = 0; jr < 4; ++jr)
      #pragma unroll
      for (int cr = 0; cr < 2; ++cr) acc1[jr][cr] = vzero;
    #pragma unroll
    for (int ks = 0; ks < 4; ++ks) {
      v4s aA[4];
      #pragma unroll
      for (int jr = 0; jr < 4; ++jr) {
        int jl = (jr << 4) + lr;
        aA[jr] = *(const v4s*)(SM + ET_OFF + (((jl << 7) + (ks << 5) + (lg << 3)) ^ ((jl & 7) << 4)));
      }
      #pragma unroll
      for (int jr = 0; jr < 4; ++jr)
        #pragma unroll
        for (int cr = 0; cr < 2; ++cr)
          acc1[jr][cr] = __builtin_amdgcn_mfma_f32_16x16x16bf16_1k(aA[jr], bfr1[cr][ks], acc1[jr][cr], 0, 0, 0);
    }

    // ---- elementwise: Y, online softmax partials, pre -> LDS ----
    #pragma unroll
    for (int jr = 0; jr < 4; ++jr) {
      #pragma unroll
      for (int reg = 0; reg < 4; ++reg) {
        int jl = (jr << 4) + (lg << 2) + reg;
        int j = (jt << 6) + jl;
        float mj = nmask[(b << 8) + j];
        size_t rowKV = (((size_t)(b << 8) + j) << 8);
        #pragma unroll
        for (int cr = 0; cr < 2; ++cr) {
          float E1 = (acc1[jr][cr][reg] + bemv[cr]) * (mi * mj);
          float Yv = qv[cr] * Kf[rowKV + cc[cr]] * (E1 + 1.0f);
          *(ushort_t*)(SM + PRE_OFF + (((jl << 9) + (cc[cr] << 1)) ^ ((jl & 7) << 4))) = f2b(yev[cr] * Yv);
          float Ym = (mj > 0.f) ? Yv : -3e38f;
          float nm = fmaxf(mloc[cr], Ym);
          float corr = __expf(mloc[cr] - nm);
          float p = mj * __expf(Ym - nm);
          lloc[cr] = lloc[cr] * corr + p;
          avloc[cr] = avloc[cr] * corr + p * Vf[rowKV + cc[cr]];
          mloc[cr] = nm;
        }
      }
    }
    __syncthreads();   // PRE ready

    // ---- GEMM2: newE_tile = PRE(64x256) @ Weout(256x64); wave: 16j x 32d ----
    v4f acc2[2] = {vzero, vzero};
    #pragma unroll
    for (int ks = 0; ks < 16; ++ks) {
      int jl = (jq << 4) + lr;
      v4s aA = *(const v4s*)(SM + PRE_OFF + (((jl << 9) + (ks << 5) + (lg << 3)) ^ ((jl & 7) << 4)));
      acc2[0] = __builtin_amdgcn_mfma_f32_16x16x16bf16_1k(aA, bfr2[0][ks], acc2[0], 0, 0, 0);
      acc2[1] = __builtin_amdgcn_mfma_f32_16x16x16bf16_1k(aA, bfr2[1][ks], acc2[1], 0, 0, 0);
    }
    // epilogue: write newE rows of this j-tile
    #pragma unroll
    for (int reg = 0; reg < 4; ++reg) {
      int j = (jt << 6) + (jq << 4) + (lg << 2) + reg;
      float mj = nmask[(b << 8) + j];
      float mm = mi * mj;
      size_t orow = (((size_t)blk << 8) + j) << 6;
      #pragma unroll
      for (int dr = 0; dr < 2; ++dr)
        newE[orow + dd[dr]] = (acc2[dr][reg] + beoV[dr]) * mm;
    }
  }

  // ---- softmax merge across the 4 lane-groups; write wvs ----
  #pragma unroll
  for (int cr = 0; cr < 2; ++cr) {
    #pragma unroll
    for (int off = 16; off <= 32; off <<= 1) {
      float m2 = __shfl_xor(mloc[cr], off, 64);
      float l2 = __shfl_xor(lloc[cr], off, 64);
      float a2 = __shfl_xor(avloc[cr], off, 64);
      float nm = fmaxf(mloc[cr], m2);
      float f1 = __expf(mloc[cr] - nm), f2n = __expf(m2 - nm);
      lloc[cr] = lloc[cr] * f1 + l2 * f2n;
      avloc[cr] = avloc[cr] * f1 + a2 * f2n;
      mloc[cr] = nm;
    }
    if (lg == 0)
      wvs[(size_t)blk * DX + cc[cr]] = yxv[cr] * (avloc[cr] / lloc[cr]);
  }

  // ---- E-stat block reduction ----
  float* RED = (float*)(SM + RED_OFF);
  RED[t] = es_s; RED[512 + t] = es_mn; RED[1024 + t] = es_mx; RED[1536 + t] = es_ss;
  __syncthreads();
  if (t < 64) {
    float s = 0.f, ss = 0.f, mn = 3e38f, mx = -3e38f;
    #pragma unroll
    for (int q = 0; q < 8; ++q) {
      s  += RED[t + (q << 6)];
      mn  = fminf(mn, RED[512 + t + (q << 6)]);
      mx  = fmaxf(mx, RED[1024 + t + (q << 6)]);
      ss += RED[1536 + t + (q << 6)];
    }
    float* eb = est + ((size_t)blk << 8);
    eb[t] = s; eb[64 + t] = mn; eb[128 + t] = mx; eb[192 + t] = ss;
  }
}

// =================== k_post: newX MFMA GEMM (Mtile=32) + y path ===================
// blocks 0..31: newX; 32..35: y path
__global__ __launch_bounds__(512) void k_post(
    const float* __restrict__ wvs, const float* __restrict__ Wxo, const float* __restrict__ bxo,
    const float* __restrict__ nmask, const float* __restrict__ y,
    const float* __restrict__ xp, const float* __restrict__ est,
    const float* __restrict__ Wyy, const float* __restrict__ byy,
    const float* __restrict__ Wxy, const float* __restrict__ bxy,
    const float* __restrict__ Wey, const float* __restrict__ bey,
    const float* __restrict__ W1, const float* __restrict__ b1,
    const float* __restrict__ W2, const float* __restrict__ b2_,
    float* __restrict__ newX, float* __restrict__ newy) {
  __shared__ char SM[16384];
  int blk = blockIdx.x, t = threadIdx.x;
  if (blk < 32) {
    int b = blk >> 3, it = blk & 7;
    #pragma unroll
    for (int h = 0; h < 2; ++h) {
      int idx = (t + (h << 9)) << 3;
      int row = idx >> 8, d0 = idx & 255;
      const float* src = wvs + ((((size_t)(b << 8) + (it << 5) + row)) << 8) + d0;
      float4 v0 = *(const float4*)src;
      float4 v1 = *(const float4*)(src + 4);
      v4u p;
      p[0] = f2b(v0.x) | ((uint32)f2b(v0.y) << 16);
      p[1] = f2b(v0.z) | ((uint32)f2b(v0.w) << 16);
      p[2] = f2b(v1.x) | ((uint32)f2b(v1.y) << 16);
      p[3] = f2b(v1.z) | ((uint32)f2b(v1.w) << 16);
      *(v4u*)(SM + SWZ_PRE(row, d0 << 1)) = p;
    }
    __syncthreads();
    int w = t >> 6, lane = t & 63, lg = lane >> 4, lr = lane & 15;
    int n0 = w << 5;
    const v4f vz = {0.f, 0.f, 0.f, 0.f};
    v4s bw[2][16];
    #pragma unroll
    for (int cr = 0; cr < 2; ++cr)
      #pragma unroll
      for (int ks = 0; ks < 16; ++ks) {
        int kk = (ks << 4) + (lg << 2);
        v4s f;
        #pragma unroll
        for (int e = 0; e < 4; ++e) f[e] = (short)f2b(Wxo[(kk + e) * DX + n0 + (cr << 4) + lr]);
        bw[cr][ks] = f;
      }
    v4f acc[2][2];
    acc[0][0] = vz; acc[0][1] = vz; acc[1][0] = vz; acc[1][1] = vz;
    #pragma unroll
    for (int ks = 0; ks < 16; ++ks) {
      v4s A[2];
      #pragma unroll
      for (int ir = 0; ir < 2; ++ir) {
        int il = (ir << 4) + lr;
        A[ir] = *(const v4s*)(SM + SWZ_PRE(il, (ks << 5) + (lg << 3)));
      }
      #pragma unroll
      for (int ir = 0; ir < 2; ++ir)
        #pragma unroll
        for (int cr = 0; cr < 2; ++cr)
          acc[ir][cr] = __builtin_amdgcn_mfma_f32_16x16x16bf16_1k(A[ir], bw[cr][ks], acc[ir][cr], 0, 0, 0);
    }
    float bb[2] = {bxo[n0 + lr], bxo[n0 + 16 + lr]};
    #pragma unroll
    for (int ir = 0; ir < 2; ++ir)
      #pragma unroll
      for (int rg = 0; rg < 4; ++rg) {
        int i = (it << 5) + (ir << 4) + (lg << 2) + rg;
        float mi = nmask[(b << 8) + i];
        size_t orow = ((size_t)(b << 8) + i) << 8;
        #pragma unroll
        for (int cr = 0; cr < 2; ++cr)
          newX[orow + n0 + (cr << 4) + lr] = (acc[ir][cr][rg] + bb[cr]) * mi;
      }
  } else {
    int b = blk - 32;
    float* sxs  = (float*)SM;        // 1024
    float* ses  = sxs + 1024;        // 256
    float* red  = ses + 256;         // 256
    float* red2 = red + 256;         // 512
    float* sny  = red2 + 512;        // 64
    float* sh   = sny + 64;          // 64
    float* sy   = sh + 64;           // 64
    // phase A: est raw reduce (512 threads, 2 i-halves) + xs finish + sy
    {
      int g = t >> 8, tt = t & 255, s = tt >> 6;
      float r = (s == 1) ? 3e38f : ((s == 2) ? -3e38f : 0.f);
      #pragma unroll 8
      for (int i2 = 0; i2 < 128; ++i2) {
        float x = est[(((size_t)(b << 8) + (g << 7) + i2) << 8) + tt];
        if (s == 0 || s == 3) r += x; else if (s == 1) r = fminf(r, x); else r = fmaxf(r, x);
      }
      red2[t] = r;
    }
    if (t < 256) {
      float meanv = 0.f;
      #pragma unroll
      for (int v = 0; v < 4; ++v) {
        float r = (v == 1) ? 3e38f : ((v == 2) ? -3e38f : 0.f);
        #pragma unroll
        for (int ch = 0; ch < 8; ++ch) {
          float x = xp[((size_t)(((b << 3) + ch) << 2) + v) * 256 + t];
          if (v == 0 || v == 3) r += x; else if (v == 1) r = fminf(r, x); else r = fmaxf(r, x);
        }
        float outv;
        if (v == 0) { meanv = r * (1.f / 256.f); outv = meanv; }
        else if (v == 3) { float var = (r - 256.f * meanv * meanv) * (1.f / 255.f); outv = sqrtf(fmaxf(var, 0.f)); }
        else outv = r;
        sxs[(v << 8) + t] = outv;
      }
    }
    if (t < 64) sy[t] = y[(b << 6) + t];
    __syncthreads();
    if (t < 256) {
      int s = (t & 255) >> 6;
      float a = red2[t], b2v = red2[256 + t];
      red[t] = (s == 0 || s == 3) ? (a + b2v) : (s == 1 ? fminf(a, b2v) : fmaxf(a, b2v));
    }
    __syncthreads();
    // phase B: est finish
    if (t < 256) {
      int stat = t >> 6, d = t & 63;
      float meanv = red[d] * (1.f / 65536.f);
      float outv;
      if (stat == 0) outv = meanv;
      else if (stat == 1) outv = red[64 + d];
      else if (stat == 2) outv = red[128 + d];
      else { float var = (red[192 + d] - 65536.f * meanv * meanv) * (1.f / 65535.f); outv = sqrtf(fmaxf(var, 0.f)); }
      ses[t] = outv;
    }
    __syncthreads();
    // phase C: big GEMV partials (split-k 4)
    int kq = t >> 6, d = t & 63;
    if (t < 256) {
      float acc = 0.f;
      #pragma unroll 4
      for (int k = kq << 4; k < (kq << 4) + 16; ++k) acc += sy[k] * Wyy[k * DY + d];
      for (int k = kq << 8; k < (kq << 8) + 256; ++k) acc += sxs[k] * Wxy[k * DY + d];
      #pragma unroll 4
      for (int k = kq << 6; k < (kq << 6) + 64; ++k) acc += ses[k] * Wey[k * DY + d];
      red[t] = acc;
    }
    __syncthreads();
    if (t < 64) sny[t] = red[t] + red[64 + t] + red[128 + t] + red[192 + t] + byy[t] + bxy[t] + bey[t];
    __syncthreads();
    if (t < 256) {
      float a = 0.f;
      #pragma unroll 4
      for (int k = kq << 4; k < (kq << 4) + 16; ++k) a += sny[k] * W1[k * DY + d];
      red[t] = a;
    }
    __syncthreads();
    if (t < 64) sh[t] = fmaxf(red[t] + red[64 + t] + red[128 + t] + red[192 + t] + b1[t], 0.f);
    __syncthreads();
    if (t < 256) {
      float a = 0.f;
      #pragma unroll 4
      for (int k = kq << 4; k < (kq << 4) + 16; ++k) a += sh[k] * W2[k * DY + d];
      red[t] = a;
    }
    __syncthreads();
    if (t < 64) newy[(b << 6) + t] = red[t] + red[64 + t] + red[128 + t] + red[192 + t] + b2_[t];
  }
}

extern "C" void kernel_launch(void* const* d_in, const int* in_sizes, int n_in,
                              void* d_out, int out_size, void* d_ws, size_t ws_size,
                              hipStream_t stream) {
  (void)in_sizes; (void)n_in; (void)out_size; (void)ws_size;
  const float* X   = (const float*)d_in[0];
  const float* E   = (const float*)d_in[1];
  const float* y   = (const float*)d_in[2];
  const float* nm  = (const float*)d_in[3];
  const float* Wq  = (const float*)d_in[4];  const float* bq  = (const float*)d_in[5];
  const float* Wk  = (const float*)d_in[6];  const float* bk  = (const float*)d_in[7];
  const float* Wv  = (const float*)d_in[8];  const float* bv  = (const float*)d_in[9];
  const float* Wem = (const float*)d_in[10]; const float* bem = (const float*)d_in[11];
  const float* Wye = (const float*)d_in[12]; const float* bye = (const float*)d_in[13];
  const float* Wyx = (const float*)d_in[14]; const float* byx = (const float*)d_in[15];
  const float* Wyy = (const float*)d_in[16]; const float* byy = (const float*)d_in[17];
  const float* Wxy = (const float*)d_in[18]; const float* bxy = (const float*)d_in[19];
  const float* Wey = (const float*)d_in[20]; const float* bey = (const float*)d_in[21];
  const float* Wxo = (const float*)d_in[22]; const float* bxo = (const float*)d_in[23];
  const float* Weo = (const float*)d_in[24]; const float* beo = (const float*)d_in[25];
  const float* W1  = (const float*)d_in[26]; const float* b1  = (const float*)d_in[27];
  const float* W2  = (const float*)d_in[28]; const float* b2  = (const float*)d_in[29];

  float* ws   = (float*)d_ws;
  float* Q    = ws;                 // 262144
  float* K    = Q + 262144;         // 262144
  float* V    = K + 262144;         // 262144
  float* yep1 = V + 262144;         // 1024
  float* yxp1 = yep1 + 1024;        // 1024
  float* wvs  = yxp1 + 1024;        // 262144
  float* est  = wvs + 262144;       // 262144
  float* xp   = est + 262144;       // 32768

  float* newX = (float*)d_out;
  float* newE = newX + 262144;
  float* newy = newE + 16777216;

  k_pre<<<132, 512, 0, stream>>>(X, nm, y, Wq, bq, Wk, bk, Wv, bv, Wye, bye, Wyx, byx,
                                 Q, K, V, xp, yep1, yxp1);
  k_main<<<BS * NN, 512, 0, stream>>>(E, nm, Wem, bem, Weo, beo, Q, K, V, yep1, yxp1,
                                      newE, wvs, est);
  k_post<<<36, 512, 0, stream>>>(wvs, Wxo, bxo, nm, y, xp, est,
                                 Wyy, byy, Wxy, bxy, Wey, bey, W1, b1, W2, b2, newX, newy);
}